// Round 8
// baseline (142.321 us; speedup 1.0000x reference)
//
#include <hip/hip_runtime.h>

// QCNN: 8 qubits, 256 amps. R20: SPLIT kernels. R16/R17/R19 showed the
// fused phase1+GEMM block fights itself (phase-1 wants 256-thread blocks
// at high occupancy — R15b ran it at 85% VALUBusy; the GEMM wants a big
// M-tile; fused at 1024 threads the 2048-thread/CU cap + barrier convoy
// gives 40% occupancy and 53% busy). R20: qcnn_s1 = R15b-verified phase-1
// at 256 threads, stores S (32MB, L3-resident) coalesced; qcnn_gemm =
// 512-thread M=64 blocks (3/CU by LDS), restage with the R18/R19-verified
// swizzle, 8 waves x 2 col-tiles x 4 m-blocks single-pass, verified REDU +
// transposed tail. Fallback to R19 fused kernel if ws too small.
// MFMA k-relabel invariance + HW-verified C/D layout as R16-R19.

#define NQ 8
#define NE 2
// ws layout (dwords): [0,65536) fragbuf; [65536,98304) U16 real;
// [98304,131072) U16 imag; [131072, +B*128) staged S16 (32MB).
#define FRAG_OFF 0
#define UR_OFF   65536
#define UI_OFF   98304
#define SG_OFF   131072

typedef _Float16 h2 __attribute__((ext_vector_type(2)));
typedef _Float16 h8 __attribute__((ext_vector_type(8)));
typedef float    f4 __attribute__((ext_vector_type(4)));

__device__ __forceinline__ float h2f(h2 v){ return __builtin_bit_cast(float, v); }
__device__ __forceinline__ h2 f2h(float v){ return __builtin_bit_cast(h2, v); }
__device__ __forceinline__ h2 u2h(unsigned u){ return __builtin_bit_cast(h2, u); }
__device__ __forceinline__ unsigned h2u(h2 v){ return __builtin_bit_cast(unsigned, v); }
__device__ __forceinline__ h2 negh(h2 v){ return u2h(h2u(v) ^ 0x80008000u); }
__device__ __forceinline__ h2 mk(float x){ return __builtin_bit_cast(h2, __builtin_amdgcn_cvt_pkrtz(x,x)); }
__device__ __forceinline__ h2 mk2(float a, float b){ return __builtin_bit_cast(h2, __builtin_amdgcn_cvt_pkrtz(a,b)); }
__device__ __forceinline__ h2 fma2h(h2 a, h2 b, h2 c){ return __builtin_elementwise_fma(a,b,c); }
__device__ __forceinline__ h2 swp(h2 v){ return __builtin_shufflevector(v,v,1,0); }

template<int CTRL>
__device__ __forceinline__ float dppf(float v){
    return __int_as_float(__builtin_amdgcn_mov_dpp(__float_as_int(v), CTRL, 0xF, 0xF, true));
}
template<int M>
__device__ __forceinline__ float sx(float v){
    if constexpr (M==1)       return dppf<0xB1>(v);
    else if constexpr (M==2)  return dppf<0x4E>(v);
    else if constexpr (M==32) return __shfl_xor(v, 32, 64);
    else return __int_as_float(__builtin_amdgcn_ds_swizzle(__float_as_int(v), (M<<10)|0x1F));
}
__device__ __forceinline__ void cmulh(h2&R, h2&I, h2 C, h2 S, h2 nS){
    h2 nR = fma2h(C, R, nS*I);
    I = fma2h(C, I, S*R);
    R = nR;
}

#define FOR_E _Pragma("unroll") for (int e = 0; e < NE; ++e)

// Fused CNOT ring (verified R2-R19): payload-combined, 2 bpermutes/elem.
#define RINGF() do { FOR_E { \
    h2 TA = pb ? B[e] : A[e]; \
    h2 TS = pb ? A[e] : B[e]; \
    int V0 = (int)__builtin_amdgcn_perm(h2u(TS), h2u(TA), 0x07060100u); \
    int V1 = (int)__builtin_amdgcn_perm(h2u(TA), h2u(TS), 0x07060100u); \
    unsigned r0 = (unsigned)__builtin_amdgcn_ds_bpermute(ba0, V0); \
    unsigned r1 = (unsigned)__builtin_amdgcn_ds_bpermute(ba1, V1); \
    A[e] = u2h(__builtin_amdgcn_perm(r1, r0, 0x07060100u)); \
    B[e] = u2h(__builtin_amdgcn_perm(r1, r0, 0x05040302u)); } \
} while(0)

// ---------------- phase-2 constants ----------------
struct P2C {
    h2 cc0,sn0,nsn0, cc1,sn1,nsn1;
    h2 uct0,ust0,nust0,usv0;
    h2 uct1,ust1,nust1;
    h2 cl1,sl1,nsl1, cp1,sp1,nsp1;
    h2 E0,E1,E2,E3,G2,G3;
    h2 Clm,Slm,nSlm,Cph,Sph,nSph;
    h2 tu1,tu3,tu5;
};

__device__ __forceinline__ P2C load_consts(const unsigned* wsu, int l){
    P2C K;
    const bool L4=(l>>4)&1, L2=(l>>2)&1, L0=l&1;
    K.cc0=u2h(wsu[0]); K.sn0=u2h(wsu[1]); K.cc1=u2h(wsu[2]); K.sn1=u2h(wsu[3]);
    K.nsn0=negh(K.sn0); K.nsn1=negh(K.sn1);
    K.uct0=u2h(wsu[4]); K.ust0=u2h(wsu[5]); K.nust0=u2h(wsu[6]); K.usv0=u2h(wsu[7]);
    K.uct1=u2h(wsu[8]); K.ust1=u2h(wsu[9]); K.nust1=u2h(wsu[10]);
    K.cl1=u2h(wsu[11]); K.sl1=u2h(wsu[12]); K.nsl1=negh(K.sl1);
    K.cp1=u2h(wsu[13]); K.sp1=u2h(wsu[14]); K.nsp1=negh(K.sp1);
    K.E0=u2h(wsu[15]); K.E1=u2h(wsu[16]); K.E2=u2h(wsu[17]);
    K.E3=u2h(wsu[18]); K.G2=u2h(wsu[19]); K.G3=u2h(wsu[20]);
    const int ki = (int)L4 + (int)L2 + (int)L0;
    K.Clm=u2h(wsu[24+ki*4+0]); K.Slm=u2h(wsu[24+ki*4+1]);
    K.Cph=u2h(wsu[24+ki*4+2]); K.Sph=u2h(wsu[24+ki*4+3]);
    K.nSlm=negh(K.Slm); K.nSph=negh(K.Sph);
    K.tu1 = L4 ? K.ust0 : K.nust0;
    K.tu3 = L2 ? K.ust0 : K.nust0;
    K.tu5 = L0 ? K.ust0 : K.nust0;
    return K;
}

// phase-2 gate ladder (R15b-verified lane code, constants from K)
#define SHF4(M) h2 oRA[NE], oIA[NE], oRB[NE], oIB[NE]; \
    FOR_E { oRA[e]=f2h(sx<M>(h2f(RA[e]))); oIA[e]=f2h(sx<M>(h2f(IA[e]))); \
            oRB[e]=f2h(sx<M>(h2f(RB[e]))); oIB[e]=f2h(sx<M>(h2f(IB[e]))); }
#define CRX_LL(CSH, M, cc, sn, nsn) do { \
    const bool ct = (l >> (CSH)) & 1; \
    SHF4(M) \
    if (ct) { FOR_E { \
        RA[e] = fma2h(cc, RA[e], (sn)*oIA[e]); IA[e] = fma2h(cc, IA[e], (nsn)*oRA[e]); \
        RB[e] = fma2h(cc, RB[e], (sn)*oIB[e]); IB[e] = fma2h(cc, IB[e], (nsn)*oRB[e]); } } \
} while(0)
#define RYC0(M, T) do { \
    SHF4(M) \
    FOR_E { \
    RA[e] = fma2h(K.uct0, RA[e], (T)*oRA[e]); IA[e] = fma2h(K.uct0, IA[e], (T)*oIA[e]); \
    RB[e] = fma2h(K.uct0, RB[e], (T)*oRB[e]); IB[e] = fma2h(K.uct0, IB[e], (T)*oIB[e]); } \
} while(0)

__device__ __forceinline__ void phase2run(const int l, const P2C& K,
    const h2* A, const h2* B, h2* RA, h2* RB, h2* IA, h2* IB)
{
    const bool L5=(l>>5)&1, L2=(l>>2)&1, L0=l&1;
    FOR_E { RA[e]=A[e]; RB[e]=B[e]; IA[e]=(h2){0,0}; IB[e]=(h2){0,0}; }

    {   h2 oA[NE], oB[NE];
        FOR_E { oA[e]=f2h(sx<16>(h2f(RA[e]))); oB[e]=f2h(sx<16>(h2f(RB[e]))); }
        if (L5){ FOR_E {
            IA[e] = K.nsn0*oA[e]; RA[e] = K.cc0*RA[e];
            IB[e] = K.nsn0*oB[e]; RB[e] = K.cc0*RB[e]; } }
    }
    CRX_LL(3, 4, K.cc0, K.sn0, K.nsn0);     // (2,3)
    CRX_LL(1, 1, K.cc0, K.sn0, K.nsn0);     // (4,5)
    FOR_E {                                  // (6,7): within B pair
        h2 oI = swp(IB[e]), oR = swp(RB[e]);
        RB[e] = fma2h(K.cc0, RB[e], K.sn0*oI);
        IB[e] = fma2h(K.cc0, IB[e], K.nsn0*oR);
    }
    CRX_LL(4, 8, K.cc0, K.sn0, K.nsn0);     // (1,2)
    CRX_LL(2, 2, K.cc0, K.sn0, K.nsn0);     // (3,4)
    if (L0) { FOR_E {                        // (5,6): A<->B elementwise
        h2 nRA = fma2h(K.cc0, RA[e], K.sn0*IB[e]);
        h2 nRB = fma2h(K.cc0, RB[e], K.sn0*IA[e]);
        h2 nIA = fma2h(K.cc0, IA[e], K.nsn0*RB[e]);
        h2 nIB = fma2h(K.cc0, IB[e], K.nsn0*RA[e]);
        RA[e]=nRA; RB[e]=nRB; IA[e]=nIA; IB[e]=nIB; } }
    FOR_E { cmulh(RA[e],IA[e],K.Clm,K.Slm,K.nSlm); cmulh(RB[e],IB[e],K.Clm,K.Slm,K.nSlm); }
    RYC0(16, K.tu1);
    RYC0(4,  K.tu3);
    RYC0(1,  K.tu5);
    FOR_E {
        h2 sA=swp(RA[e]), sB=swp(RB[e]), tA=swp(IA[e]), tB=swp(IB[e]);
        RA[e] = fma2h(K.uct0, RA[e], K.usv0*sA); RB[e] = fma2h(K.uct0, RB[e], K.usv0*sB);
        IA[e] = fma2h(K.uct0, IA[e], K.usv0*tA); IB[e] = fma2h(K.uct0, IB[e], K.usv0*tB);
    }
    FOR_E { cmulh(RA[e],IA[e],K.Cph,K.Sph,K.nSph); cmulh(RB[e],IB[e],K.Cph,K.Sph,K.nSph); }

    CRX_LL(4, 4, K.cc1, K.sn1, K.nsn1);     // (1,3)
    if (L0) { FOR_E {
        h2 sIA=swp(IA[e]), sRA=swp(RA[e]), sIB=swp(IB[e]), sRB=swp(RB[e]);
        RA[e] = fma2h(K.cc1, RA[e], K.sn1*sIA); IA[e] = fma2h(K.cc1, IA[e], K.nsn1*sRA);
        RB[e] = fma2h(K.cc1, RB[e], K.sn1*sIB); IB[e] = fma2h(K.cc1, IB[e], K.nsn1*sRB); } }
    CRX_LL(2, 1, K.cc1, K.sn1, K.nsn1);     // (3,5)
    {
        if (L2){ FOR_E { cmulh(RA[e],IA[e],K.cl1,K.sl1,K.nsl1); cmulh(RB[e],IB[e],K.cl1,K.sl1,K.nsl1); } }
        h2 T = L2 ? K.ust1 : K.nust1;
        SHF4(4)
        FOR_E {
            RA[e] = fma2h(K.uct1, RA[e], T*oRA[e]); IA[e] = fma2h(K.uct1, IA[e], T*oIA[e]);
            RB[e] = fma2h(K.uct1, RB[e], T*oRB[e]); IB[e] = fma2h(K.uct1, IB[e], T*oIB[e]);
        }
        if (L2){ FOR_E { cmulh(RA[e],IA[e],K.cp1,K.sp1,K.nsp1); cmulh(RB[e],IB[e],K.cp1,K.sp1,K.nsp1); } }
    }
    FOR_E {
        h2 sR=swp(RA[e]), sI=swp(IA[e]);
        h2 nR = fma2h(K.E3,sI, fma2h(K.E2,IA[e], fma2h(K.E1,sR, K.E0*RA[e])));
        h2 nI = fma2h(K.G3,sR, fma2h(K.G2,RA[e], fma2h(K.E1,sI, K.E0*IA[e])));
        RA[e]=nR; IA[e]=nI;
        h2 sR2=swp(RB[e]), sI2=swp(IB[e]);
        h2 nR2 = fma2h(K.E3,sI2, fma2h(K.E2,IB[e], fma2h(K.E1,sR2, K.E0*RB[e])));
        h2 nI2 = fma2h(K.G3,sR2, fma2h(K.G2,RB[e], fma2h(K.E1,sI2, K.E0*IB[e])));
        RB[e]=nR2; IB[e]=nI2;
    }
}

// ---- shared phase-1 macros ----
#define RY_L(q, M) do { FOR_E { \
    h2 oA = f2h(sx<M>(h2f(A[e]))), oB = f2h(sx<M>(h2f(B[e]))); \
    A[e] = fma2h(cH[e][q], A[e], tsH[e][q]*oA); \
    B[e] = fma2h(cH[e][q], B[e], tsH[e][q]*oB); } \
} while(0)

#define LADDER() do { \
    RINGF(); \
    _Pragma("unroll") for(int cyc=0;cyc<3;++cyc){ \
        RY_L(0,32); RY_L(1,16); RY_L(2,8); RY_L(3,4); RY_L(4,2); RY_L(5,1); \
        FOR_E { h2 nA = fma2h(c6h[e], A[e], ns6h[e]*B[e]); \
                h2 nB = fma2h(s6h[e], A[e], c6h[e]*B[e]); \
                A[e]=nA; B[e]=nB; } \
        FOR_E { A[e] = fma2h(c7h[e], A[e], sv7h[e]*swp(A[e])); \
                B[e] = fma2h(c7h[e], B[e], sv7h[e]*swp(B[e])); } \
        if (cyc < 2) RINGF(); \
    } \
} while(0)

#define BUILD_COEF_INLINE(eeexpr) FOR_E { \
    int ee = (eeexpr); if (ee >= Btot) ee = Btot - 1; \
    const float4* xv = (const float4*)(x + ee*NQ); \
    float4 xa=xv[0], xb=xv[1]; \
    float ang[8]={xa.x,xa.y,xa.z,xa.w,xb.x,xb.y,xb.z,xb.w}; \
    float cq[8], sq[8]; \
    _Pragma("unroll") for(int q=0;q<8;++q) __sincosf(0.5f*ang[q], &sq[q], &cq[q]); \
    _Pragma("unroll") for(int q=0;q<6;++q){ \
        cH[e][q]=mk(cq[q]); \
        tsH[e][q]=u2h(h2u(mk(sq[q])) ^ sm[q]); } \
    c6h[e]=mk(cq[6]); s6h[e]=mk(sq[6]); ns6h[e]=negh(s6h[e]); \
    c7h[e]=mk(cq[7]); sv7h[e]=mk2(-sq[7], sq[7]); \
    float pl = (L5?sq[0]:cq[0])*(L4?sq[1]:cq[1])*(L3?sq[2]:cq[2]) \
             * (L2?sq[3]:cq[3])*(L1?sq[4]:cq[4])*(L0?sq[5]:cq[5]); \
    float pc6=pl*cq[6], ps6=pl*sq[6]; \
    A[e] = mk2(pc6*cq[7], pc6*sq[7]); \
    B[e] = mk2(ps6*cq[7], ps6*sq[7]); \
}

#define REDU(aR, aI, mb, CT) do { \
    _Pragma("unroll") for (int r = 0; r < 4; ++r){ \
        float nv = fmaf(aR[r], aR[r], aI[r]*aI[r]); \
        float o  = sx<1>(nv); \
        float v0 = nv + o, v1 = nv - o; \
        v0 += sx<2>(v0); v1 += sx<2>(v1); \
        v0 += sx<4>(v0); v1 += sx<4>(v1); \
        v0 += sx<8>(v0); v1 += sx<8>(v1); \
        if ((l & 15) == 0){ \
            parts[0][(mb)*16 + g*4 + r][CT] = v0; \
            parts[1][(mb)*16 + g*4 + r][CT] = v1; } \
    } \
} while(0)

// ---- prep_u: 8 blocks x 1024. Each wave builds ONE basis pair. ----
__global__ __launch_bounds__(1024) void qcnn_prep_u(
    const float* __restrict__ crx, const float* __restrict__ u3p,
    unsigned* __restrict__ ws)
{
    __shared__ unsigned cws[48];
    if (threadIdx.x == 0){
        auto PK=[](float lo, float hi)->unsigned{
            unsigned a=__builtin_bit_cast(unsigned short,(_Float16)lo);
            unsigned b=__builtin_bit_cast(unsigned short,(_Float16)hi);
            return a | (b<<16);
        };
        float sc0,cc0,sc1,cc1;
        __sincosf(0.5f*crx[0],&sc0,&cc0);
        __sincosf(0.5f*crx[1],&sc1,&cc1);
        cws[0]=PK(cc0,cc0); cws[1]=PK(sc0,sc0); cws[2]=PK(cc1,cc1); cws[3]=PK(sc1,sc1);
        float th0=u3p[0], ph0=u3p[1], lm0=u3p[2];
        float ust0,uct0; __sincosf(0.5f*th0,&ust0,&uct0);
        cws[4]=PK(uct0,uct0); cws[5]=PK(ust0,ust0); cws[6]=PK(-ust0,-ust0); cws[7]=PK(-ust0,ust0);
        float th1=u3p[3], ph1=u3p[4], lm1=u3p[5];
        float ust1,uct1; __sincosf(0.5f*th1,&ust1,&uct1);
        float sl1,cl1;   __sincosf(lm1,&sl1,&cl1);
        float sp1,cp1;   __sincosf(ph1,&sp1,&cp1);
        cws[8]=PK(uct1,uct1); cws[9]=PK(ust1,ust1); cws[10]=PK(-ust1,-ust1);
        cws[11]=PK(cl1,cl1); cws[12]=PK(sl1,sl1); cws[13]=PK(cp1,cp1); cws[14]=PK(sp1,sp1);
        float cpl1=cp1*cl1-sp1*sl1, spl1=sp1*cl1+cp1*sl1;
        float u01r=-ust1*cl1, u01i=-ust1*sl1;
        float u10r= ust1*cp1, u10i= ust1*sp1;
        float u11r= uct1*cpl1, u11i= uct1*spl1;
        cws[15]=PK(uct1,u11r); cws[16]=PK(u01r,u10r); cws[17]=PK(0.f,-u11i);
        cws[18]=PK(-u01i,-u10i); cws[19]=PK(0.f,u11i); cws[20]=PK(u01i,u10i);
        for(int k=0;k<4;++k){
            float kf=(float)k, sA,cA,sB,cB,sA2,cA2,sB2,cB2;
            __sincosf(lm0*kf,      &sA,&cA);
            __sincosf(lm0*(kf+1.f),&sB,&cB);
            __sincosf(ph0*kf,      &sA2,&cA2);
            __sincosf(ph0*(kf+1.f),&sB2,&cB2);
            unsigned* q = cws + 24 + k*4;
            q[0]=PK(cA,cB); q[1]=PK(sA,sB); q[2]=PK(cA2,cB2); q[3]=PK(sA2,sB2);
        }
    }
    __syncthreads();

    const int l = threadIdx.x & 63;
    const int w = threadIdx.x >> 6;
    const P2C K = load_consts(cws, l);
    const bool pb = __builtin_popcount(l) & 1;
    const int ba0 = (((l&32)|((l^(l>>1))&31)) << 2);
    const int ba1 = ba0 ^ (48<<2);

    const int j0 = blockIdx.x*32 + w*2;
    h2 A[NE], B[NE];
    FOR_E {
        A[e]=(h2){0,0}; B[e]=(h2){0,0};
        const int j = j0 + e;
        if (l == (j >> 2)){
            const int slot = j & 3;
            const _Float16 one = (_Float16)1.f;
            if      (slot==0) A[e].x = one;
            else if (slot==1) A[e].y = one;
            else if (slot==2) B[e].x = one;
            else              B[e].y = one;
        }
    }
    RINGF();
    h2 RA[NE], RB[NE], IA[NE], IB[NE];
    phase2run(l, K, A, B, RA, RB, IA, IB);
    FOR_E {
        const int j = j0 + e;
        *(uint2*)(ws + UR_OFF + j*128 + l*2) = make_uint2(h2u(RA[e]), h2u(RB[e]));
        *(uint2*)(ws + UI_OFF + j*128 + l*2) = make_uint2(h2u(IA[e]), h2u(IB[e]));
    }
}

// ---- prep_frag: repack U16 into B-fragment order. 256 chunks x 64 lanes.
__global__ void qcnn_prep_frag(unsigned* __restrict__ ws){
    const int T = blockIdx.x*256 + threadIdx.x;
    const int chunk = T >> 6, l = T & 63;
    const int ct = chunk >> 4, ri = (chunk >> 3) & 1, ks = chunk & 7;
    const unsigned short* U = (const unsigned short*)(ws + (ri ? UI_OFF : UR_OFF));
    const int n = ct*16 + (l & 15);
    const int g = l >> 4;
    unsigned d[4];
#pragma unroll
    for (int p = 0; p < 4; ++p){
        const int k0 = ks*32 + g*8 + 2*p;
        unsigned lo = U[k0*256 + n];
        unsigned hi = U[(k0+1)*256 + n];
        d[p] = lo | (hi << 16);
    }
    uint4 v; v.x=d[0]; v.y=d[1]; v.z=d[2]; v.w=d[3];
    *(uint4*)(ws + FRAG_OFF + chunk*256 + l*4) = v;
}

// ---- s1: phase-1 only, R15b-verified 256-thread structure; stores S. ----
__global__ __launch_bounds__(256) void qcnn_s1(
    const float* __restrict__ x, unsigned* __restrict__ ws, int Btot)
{
    const int gtid = blockIdx.x*256 + threadIdx.x;
    const int wv = gtid >> 6;
    const int l = threadIdx.x & 63;
    const int e0 = wv * NE;
    if (e0 >= Btot) return;
    const bool L5=(l>>5)&1, L4=(l>>4)&1, L3=(l>>3)&1, L2=(l>>2)&1, L1=(l>>1)&1, L0=l&1;
    const bool pb = __builtin_popcount(l) & 1;
    const int ba0 = (((l&32)|((l^(l>>1))&31)) << 2);
    const int ba1 = ba0 ^ (48<<2);
    const bool bits[6]={L5,L4,L3,L2,L1,L0};
    unsigned sm[6];
#pragma unroll
    for(int q=0;q<6;++q) sm[q] = bits[q] ? 0u : 0x80008000u;

    h2 cH[NE][6], tsH[NE][6];
    h2 c6h[NE], s6h[NE], ns6h[NE], c7h[NE], sv7h[NE];
    h2 A[NE], B[NE];
    BUILD_COEF_INLINE(e0 + e);
    LADDER();        // final ring absorbed into U (prep_u)
    FOR_E {
        const int ee = e0 + e;
        if (ee < Btot)
            *(uint2*)(ws + SG_OFF + ee*128 + l*2) = make_uint2(h2u(A[e]), h2u(B[e]));
    }
}

// ---- gemm: 512 threads, M=64. Restage S global->LDS (verified swizzle),
// 8 waves x 2 col-tiles x 4 m-blocks single-pass, REDU + transposed tail. ----
__global__ __launch_bounds__(512) void qcnn_gemm(
    const unsigned* __restrict__ wsu,
    const float* __restrict__ w1,
    const float* __restrict__ b1,
    const float* __restrict__ w2,
    const float* __restrict__ b2,
    float* __restrict__ out,
    int Btot)
{
    __shared__ __align__(16) unsigned char Sl[32*1024];
    __shared__ float parts[2][64][17];
    const int tid = threadIdx.x;
    const int l = tid & 63;
    const int w = tid >> 6;                  // wave 0..7
    const int eblk = blockIdx.x * 64;

    // restage: coalesced global read, verified-swizzle LDS write
#pragma unroll
    for (int i = 0; i < 8; ++i){
        const int idx = tid + i*512;
        const int r = idx >> 6, ll = idx & 63;
        int ee = eblk + r; if (ee >= Btot) ee = Btot - 1;
        uint2 v = *(const uint2*)(wsu + SG_OFF + ee*128 + ll*2);
        const int mblk = r >> 4, rr = r & 15;
        const int ks = ll >> 3, g2 = (ll >> 1) & 3, pp = ll & 1;
        const unsigned gran = (unsigned)((rr | (g2<<4)) ^ ks ^ (g2<<1));
        const unsigned off = (unsigned)(((mblk*8 + ks) << 10) | (gran << 4) | (pp << 3));
        *(uint2*)(Sl + off) = v;
    }
    __syncthreads();

    const int g = l >> 4;
    const unsigned* frag = wsu + FRAG_OFF;
#pragma unroll
    for (int j = 0; j < 2; ++j){
        const int ct = w*2 + j;
        f4 aR0={0,0,0,0}, aI0={0,0,0,0}, aR1={0,0,0,0}, aI1={0,0,0,0};
        f4 aR2={0,0,0,0}, aI2={0,0,0,0}, aR3={0,0,0,0}, aI3={0,0,0,0};
#pragma unroll
        for (int ks = 0; ks < 8; ++ks){
            h8 br = *(const h8*)(frag + (ct*16 +     ks)*256 + l*4);
            h8 bi = *(const h8*)(frag + (ct*16 + 8 + ks)*256 + l*4);
            const unsigned ga = (unsigned)((l ^ ks ^ (g<<1)) << 4);
            h8 a0 = *(const h8*)(Sl + ((0*8 + ks) << 10) + ga);
            h8 a1 = *(const h8*)(Sl + ((1*8 + ks) << 10) + ga);
            h8 a2 = *(const h8*)(Sl + ((2*8 + ks) << 10) + ga);
            h8 a3 = *(const h8*)(Sl + ((3*8 + ks) << 10) + ga);
            aR0 = __builtin_amdgcn_mfma_f32_16x16x32_f16(a0, br, aR0, 0, 0, 0);
            aI0 = __builtin_amdgcn_mfma_f32_16x16x32_f16(a0, bi, aI0, 0, 0, 0);
            aR1 = __builtin_amdgcn_mfma_f32_16x16x32_f16(a1, br, aR1, 0, 0, 0);
            aI1 = __builtin_amdgcn_mfma_f32_16x16x32_f16(a1, bi, aI1, 0, 0, 0);
            aR2 = __builtin_amdgcn_mfma_f32_16x16x32_f16(a2, br, aR2, 0, 0, 0);
            aI2 = __builtin_amdgcn_mfma_f32_16x16x32_f16(a2, bi, aI2, 0, 0, 0);
            aR3 = __builtin_amdgcn_mfma_f32_16x16x32_f16(a3, br, aR3, 0, 0, 0);
            aI3 = __builtin_amdgcn_mfma_f32_16x16x32_f16(a3, bi, aI3, 0, 0, 0);
        }
        REDU(aR0, aI0, 0, ct);
        REDU(aR1, aI1, 1, ct);
        REDU(aR2, aI2, 2, ct);
        REDU(aR3, aI3, 3, ct);
    }
    __syncthreads();

    // tail (R18/R19-verified), two halves of 32 elems each
#pragma unroll
    for (int half = 0; half < 2; ++half){
        const int elem = (tid >> 4) + half*32;
        const int k = tid & 15;
        float F0 = parts[0][elem][k];
        float F1 = parts[1][elem][k];
        F0 = __int_as_float(__float_as_int(F0) ^ ((k & 1) << 31));  // s3 = (-1)^(ct&1)
        F0 += sx<1>(F0); F0 += sx<2>(F0); F0 += sx<4>(F0); F0 += sx<8>(F0);
        F1 += sx<1>(F1); F1 += sx<2>(F1); F1 += sx<4>(F1); F1 += sx<8>(F1);
        float contrib = 0.0f;
        if (k < 10){
            float z = fmaf(F0, w1[k], fmaf(F1, w1[10+k], b1[k]));
            float ex = __expf(2.0f*z);
            contrib = ((ex-1.0f)/(ex+1.0f)) * w2[k];
        }
        contrib += sx<1>(contrib);
        contrib += sx<2>(contrib);
        contrib += sx<4>(contrib);
        contrib += sx<8>(contrib);
        if (k == 0 && eblk + elem < Btot){
            out[eblk + elem] = 1.0f/(1.0f + __expf(-(contrib + b2[0])));
        }
    }
}

// ---- fallback: R19 fused kernel (verified) ----
__global__ __launch_bounds__(1024) void qcnn_fused(
    const float* __restrict__ x,
    const unsigned* __restrict__ wsu,
    const float* __restrict__ w1,
    const float* __restrict__ b1,
    const float* __restrict__ w2,
    const float* __restrict__ b2,
    float* __restrict__ out,
    int Btot)
{
    __shared__ __align__(16) unsigned char Sl[32*1024];
    __shared__ float parts[2][64][17];
    const int tid = threadIdx.x;
    const int l = tid & 63;
    const int w = tid >> 6;
    const int eblk = blockIdx.x * 64;
    const bool L5=(l>>5)&1, L4=(l>>4)&1, L3=(l>>3)&1, L2=(l>>2)&1, L1=(l>>1)&1, L0=l&1;
    const bool pb = __builtin_popcount(l) & 1;
    const int ba0 = (((l&32)|((l^(l>>1))&31)) << 2);
    const int ba1 = ba0 ^ (48<<2);
    const bool bits[6]={L5,L4,L3,L2,L1,L0};
    unsigned sm[6];
#pragma unroll
    for(int q=0;q<6;++q) sm[q] = bits[q] ? 0u : 0x80008000u;

#pragma unroll
    for (int pass = 0; pass < 2; ++pass){
        const int rbase = w*4 + pass*2;
        h2 cH[NE][6], tsH[NE][6];
        h2 c6h[NE], s6h[NE], ns6h[NE], c7h[NE], sv7h[NE];
        h2 A[NE], B[NE];
        BUILD_COEF_INLINE(eblk + rbase + e);
        LADDER();
        FOR_E {
            const int r = rbase + e;
            const int mblk = r >> 4, rr = r & 15;
            const int ks = l >> 3, g2 = (l >> 1) & 3, pp = l & 1;
            const unsigned gran = (unsigned)((rr | (g2<<4)) ^ ks ^ (g2<<1));
            const unsigned off = (unsigned)(((mblk*8 + ks) << 10) | (gran << 4) | (pp << 3));
            *(uint2*)(Sl + off) = make_uint2(h2u(A[e]), h2u(B[e]));
        }
    }
    __syncthreads();

    const int g = l >> 4;
    const unsigned* frag = wsu + FRAG_OFF;
#pragma unroll
    for (int half = 0; half < 2; ++half){
        f4 aRa={0,0,0,0}, aIa={0,0,0,0}, aRb={0,0,0,0}, aIb={0,0,0,0};
        const int mb0 = half*2, mb1 = half*2 + 1;
#pragma unroll
        for (int ks = 0; ks < 8; ++ks){
            h8 br = *(const h8*)(frag + (w*16 +     ks)*256 + l*4);
            h8 bi = *(const h8*)(frag + (w*16 + 8 + ks)*256 + l*4);
            const unsigned ga = (unsigned)((l ^ ks ^ (g<<1)) << 4);
            h8 a0 = *(const h8*)(Sl + ((mb0*8 + ks) << 10) + ga);
            h8 a1 = *(const h8*)(Sl + ((mb1*8 + ks) << 10) + ga);
            aRa = __builtin_amdgcn_mfma_f32_16x16x32_f16(a0, br, aRa, 0, 0, 0);
            aIa = __builtin_amdgcn_mfma_f32_16x16x32_f16(a0, bi, aIa, 0, 0, 0);
            aRb = __builtin_amdgcn_mfma_f32_16x16x32_f16(a1, br, aRb, 0, 0, 0);
            aIb = __builtin_amdgcn_mfma_f32_16x16x32_f16(a1, bi, aIb, 0, 0, 0);
        }
        REDU(aRa, aIa, mb0, w);
        REDU(aRb, aIb, mb1, w);
    }
    __syncthreads();

    {
        const int elem = tid >> 4, k = tid & 15;
        float F0 = parts[0][elem][k];
        float F1 = parts[1][elem][k];
        F0 = __int_as_float(__float_as_int(F0) ^ ((k & 1) << 31));
        F0 += sx<1>(F0); F0 += sx<2>(F0); F0 += sx<4>(F0); F0 += sx<8>(F0);
        F1 += sx<1>(F1); F1 += sx<2>(F1); F1 += sx<4>(F1); F1 += sx<8>(F1);
        float contrib = 0.0f;
        if (k < 10){
            float z = fmaf(F0, w1[k], fmaf(F1, w1[10+k], b1[k]));
            float ex = __expf(2.0f*z);
            contrib = ((ex-1.0f)/(ex+1.0f)) * w2[k];
        }
        contrib += sx<1>(contrib);
        contrib += sx<2>(contrib);
        contrib += sx<4>(contrib);
        contrib += sx<8>(contrib);
        if (k == 0 && eblk + elem < Btot){
            out[eblk + elem] = 1.0f/(1.0f + __expf(-(contrib + b2[0])));
        }
    }
}

extern "C" void kernel_launch(void* const* d_in, const int* in_sizes, int n_in,
                              void* d_out, int out_size, void* d_ws, size_t ws_size,
                              hipStream_t stream) {
    const float* x   = (const float*)d_in[0];
    const float* crx = (const float*)d_in[1];
    const float* u3p = (const float*)d_in[2];
    const float* w1  = (const float*)d_in[3];
    const float* b1  = (const float*)d_in[4];
    const float* w2  = (const float*)d_in[5];
    const float* b2  = (const float*)d_in[6];
    float* out = (float*)d_out;
    unsigned* ws = (unsigned*)d_ws;

    const int B = in_sizes[0] / NQ;              // 65536
    hipLaunchKernelGGL(qcnn_prep_u,    dim3(8),  dim3(1024), 0, stream, crx, u3p, ws);
    hipLaunchKernelGGL(qcnn_prep_frag, dim3(64), dim3(256),  0, stream, ws);

    const size_t need = ((size_t)SG_OFF + (size_t)B * 128) * 4;
    if (ws_size >= need) {
        hipLaunchKernelGGL(qcnn_s1, dim3((B + 7) / 8), dim3(256), 0, stream,
                           x, ws, B);
        hipLaunchKernelGGL(qcnn_gemm, dim3((B + 63) / 64), dim3(512), 0, stream,
                           ws, w1, b1, w2, b2, out, B);
    } else {
        hipLaunchKernelGGL(qcnn_fused, dim3((B + 63) / 64), dim3(1024), 0, stream,
                           x, ws, w1, b1, w2, b2, out, B);
    }
}

// Round 9
// 117.743 us; speedup vs baseline: 1.2088x; 1.2088x over previous
//
#include <hip/hip_runtime.h>

// QCNN: 8 qubits, 256 amps. R21: fused, 512-thread / 8-wave blocks, M=64.
// R20 taught: (a) every iteration carries a fixed 46.5us workspace zero-fill
// (268MB) inside the timed region — kernel-sum is what we control; (b) the
// split's S round-trip + extra launches cost more than fusion saved; (c)
// across R16/R19 the occupancy lever dominated: M=32@70% beat M=64@40%.
// R21 gets BOTH: 512 threads x 41.5KB LDS = 3 blocks/CU = 24 waves (75%),
// M=64 keeps frag L2 traffic at 256MB. Phase-1 = 4 register-scoped passes
// (R19 spill-free pattern, unroll 1); GEMM = 2 ct x 2 mb-halves per wave,
// 16 live acc (unroll 1 outer loops). All pieces correctness-verified in
// R18-R20: staging swizzle gran^ks^(g<<1), padded parts[2][64][17],
// sign-folded REDU, transposed tail, HW-verified C/D layout.

#define NQ 8
#define NE 2
// ws layout (dwords): [0,65536) fragbuf; [65536,98304) U16 real;
// [98304,131072) U16 imag.
#define FRAG_OFF 0
#define UR_OFF   65536
#define UI_OFF   98304

typedef _Float16 h2 __attribute__((ext_vector_type(2)));
typedef _Float16 h8 __attribute__((ext_vector_type(8)));
typedef float    f4 __attribute__((ext_vector_type(4)));

__device__ __forceinline__ float h2f(h2 v){ return __builtin_bit_cast(float, v); }
__device__ __forceinline__ h2 f2h(float v){ return __builtin_bit_cast(h2, v); }
__device__ __forceinline__ h2 u2h(unsigned u){ return __builtin_bit_cast(h2, u); }
__device__ __forceinline__ unsigned h2u(h2 v){ return __builtin_bit_cast(unsigned, v); }
__device__ __forceinline__ h2 negh(h2 v){ return u2h(h2u(v) ^ 0x80008000u); }
__device__ __forceinline__ h2 mk(float x){ return __builtin_bit_cast(h2, __builtin_amdgcn_cvt_pkrtz(x,x)); }
__device__ __forceinline__ h2 mk2(float a, float b){ return __builtin_bit_cast(h2, __builtin_amdgcn_cvt_pkrtz(a,b)); }
__device__ __forceinline__ h2 fma2h(h2 a, h2 b, h2 c){ return __builtin_elementwise_fma(a,b,c); }
__device__ __forceinline__ h2 swp(h2 v){ return __builtin_shufflevector(v,v,1,0); }

template<int CTRL>
__device__ __forceinline__ float dppf(float v){
    return __int_as_float(__builtin_amdgcn_mov_dpp(__float_as_int(v), CTRL, 0xF, 0xF, true));
}
template<int M>
__device__ __forceinline__ float sx(float v){
    if constexpr (M==1)       return dppf<0xB1>(v);
    else if constexpr (M==2)  return dppf<0x4E>(v);
    else if constexpr (M==32) return __shfl_xor(v, 32, 64);
    else return __int_as_float(__builtin_amdgcn_ds_swizzle(__float_as_int(v), (M<<10)|0x1F));
}
__device__ __forceinline__ void cmulh(h2&R, h2&I, h2 C, h2 S, h2 nS){
    h2 nR = fma2h(C, R, nS*I);
    I = fma2h(C, I, S*R);
    R = nR;
}

#define FOR_E _Pragma("unroll") for (int e = 0; e < NE; ++e)

// Fused CNOT ring (verified R2-R20): payload-combined, 2 bpermutes/elem.
#define RINGF() do { FOR_E { \
    h2 TA = pb ? B[e] : A[e]; \
    h2 TS = pb ? A[e] : B[e]; \
    int V0 = (int)__builtin_amdgcn_perm(h2u(TS), h2u(TA), 0x07060100u); \
    int V1 = (int)__builtin_amdgcn_perm(h2u(TA), h2u(TS), 0x07060100u); \
    unsigned r0 = (unsigned)__builtin_amdgcn_ds_bpermute(ba0, V0); \
    unsigned r1 = (unsigned)__builtin_amdgcn_ds_bpermute(ba1, V1); \
    A[e] = u2h(__builtin_amdgcn_perm(r1, r0, 0x07060100u)); \
    B[e] = u2h(__builtin_amdgcn_perm(r1, r0, 0x05040302u)); } \
} while(0)

// ---------------- phase-2 constants ----------------
struct P2C {
    h2 cc0,sn0,nsn0, cc1,sn1,nsn1;
    h2 uct0,ust0,nust0,usv0;
    h2 uct1,ust1,nust1;
    h2 cl1,sl1,nsl1, cp1,sp1,nsp1;
    h2 E0,E1,E2,E3,G2,G3;
    h2 Clm,Slm,nSlm,Cph,Sph,nSph;
    h2 tu1,tu3,tu5;
};

__device__ __forceinline__ P2C load_consts(const unsigned* wsu, int l){
    P2C K;
    const bool L4=(l>>4)&1, L2=(l>>2)&1, L0=l&1;
    K.cc0=u2h(wsu[0]); K.sn0=u2h(wsu[1]); K.cc1=u2h(wsu[2]); K.sn1=u2h(wsu[3]);
    K.nsn0=negh(K.sn0); K.nsn1=negh(K.sn1);
    K.uct0=u2h(wsu[4]); K.ust0=u2h(wsu[5]); K.nust0=u2h(wsu[6]); K.usv0=u2h(wsu[7]);
    K.uct1=u2h(wsu[8]); K.ust1=u2h(wsu[9]); K.nust1=u2h(wsu[10]);
    K.cl1=u2h(wsu[11]); K.sl1=u2h(wsu[12]); K.nsl1=negh(K.sl1);
    K.cp1=u2h(wsu[13]); K.sp1=u2h(wsu[14]); K.nsp1=negh(K.sp1);
    K.E0=u2h(wsu[15]); K.E1=u2h(wsu[16]); K.E2=u2h(wsu[17]);
    K.E3=u2h(wsu[18]); K.G2=u2h(wsu[19]); K.G3=u2h(wsu[20]);
    const int ki = (int)L4 + (int)L2 + (int)L0;
    K.Clm=u2h(wsu[24+ki*4+0]); K.Slm=u2h(wsu[24+ki*4+1]);
    K.Cph=u2h(wsu[24+ki*4+2]); K.Sph=u2h(wsu[24+ki*4+3]);
    K.nSlm=negh(K.Slm); K.nSph=negh(K.Sph);
    K.tu1 = L4 ? K.ust0 : K.nust0;
    K.tu3 = L2 ? K.ust0 : K.nust0;
    K.tu5 = L0 ? K.ust0 : K.nust0;
    return K;
}

// phase-2 gate ladder (R15b-verified lane code, constants from K)
#define SHF4(M) h2 oRA[NE], oIA[NE], oRB[NE], oIB[NE]; \
    FOR_E { oRA[e]=f2h(sx<M>(h2f(RA[e]))); oIA[e]=f2h(sx<M>(h2f(IA[e]))); \
            oRB[e]=f2h(sx<M>(h2f(RB[e]))); oIB[e]=f2h(sx<M>(h2f(IB[e]))); }
#define CRX_LL(CSH, M, cc, sn, nsn) do { \
    const bool ct = (l >> (CSH)) & 1; \
    SHF4(M) \
    if (ct) { FOR_E { \
        RA[e] = fma2h(cc, RA[e], (sn)*oIA[e]); IA[e] = fma2h(cc, IA[e], (nsn)*oRA[e]); \
        RB[e] = fma2h(cc, RB[e], (sn)*oIB[e]); IB[e] = fma2h(cc, IB[e], (nsn)*oRB[e]); } } \
} while(0)
#define RYC0(M, T) do { \
    SHF4(M) \
    FOR_E { \
    RA[e] = fma2h(K.uct0, RA[e], (T)*oRA[e]); IA[e] = fma2h(K.uct0, IA[e], (T)*oIA[e]); \
    RB[e] = fma2h(K.uct0, RB[e], (T)*oRB[e]); IB[e] = fma2h(K.uct0, IB[e], (T)*oIB[e]); } \
} while(0)

__device__ __forceinline__ void phase2run(const int l, const P2C& K,
    const h2* A, const h2* B, h2* RA, h2* RB, h2* IA, h2* IB)
{
    const bool L5=(l>>5)&1, L2=(l>>2)&1, L0=l&1;
    FOR_E { RA[e]=A[e]; RB[e]=B[e]; IA[e]=(h2){0,0}; IB[e]=(h2){0,0}; }

    {   h2 oA[NE], oB[NE];
        FOR_E { oA[e]=f2h(sx<16>(h2f(RA[e]))); oB[e]=f2h(sx<16>(h2f(RB[e]))); }
        if (L5){ FOR_E {
            IA[e] = K.nsn0*oA[e]; RA[e] = K.cc0*RA[e];
            IB[e] = K.nsn0*oB[e]; RB[e] = K.cc0*RB[e]; } }
    }
    CRX_LL(3, 4, K.cc0, K.sn0, K.nsn0);     // (2,3)
    CRX_LL(1, 1, K.cc0, K.sn0, K.nsn0);     // (4,5)
    FOR_E {                                  // (6,7): within B pair
        h2 oI = swp(IB[e]), oR = swp(RB[e]);
        RB[e] = fma2h(K.cc0, RB[e], K.sn0*oI);
        IB[e] = fma2h(K.cc0, IB[e], K.nsn0*oR);
    }
    CRX_LL(4, 8, K.cc0, K.sn0, K.nsn0);     // (1,2)
    CRX_LL(2, 2, K.cc0, K.sn0, K.nsn0);     // (3,4)
    if (L0) { FOR_E {                        // (5,6): A<->B elementwise
        h2 nRA = fma2h(K.cc0, RA[e], K.sn0*IB[e]);
        h2 nRB = fma2h(K.cc0, RB[e], K.sn0*IA[e]);
        h2 nIA = fma2h(K.cc0, IA[e], K.nsn0*RB[e]);
        h2 nIB = fma2h(K.cc0, IB[e], K.nsn0*RA[e]);
        RA[e]=nRA; RB[e]=nRB; IA[e]=nIA; IB[e]=nIB; } }
    FOR_E { cmulh(RA[e],IA[e],K.Clm,K.Slm,K.nSlm); cmulh(RB[e],IB[e],K.Clm,K.Slm,K.nSlm); }
    RYC0(16, K.tu1);
    RYC0(4,  K.tu3);
    RYC0(1,  K.tu5);
    FOR_E {
        h2 sA=swp(RA[e]), sB=swp(RB[e]), tA=swp(IA[e]), tB=swp(IB[e]);
        RA[e] = fma2h(K.uct0, RA[e], K.usv0*sA); RB[e] = fma2h(K.uct0, RB[e], K.usv0*sB);
        IA[e] = fma2h(K.uct0, IA[e], K.usv0*tA); IB[e] = fma2h(K.uct0, IB[e], K.usv0*tB);
    }
    FOR_E { cmulh(RA[e],IA[e],K.Cph,K.Sph,K.nSph); cmulh(RB[e],IB[e],K.Cph,K.Sph,K.nSph); }

    CRX_LL(4, 4, K.cc1, K.sn1, K.nsn1);     // (1,3)
    if (L0) { FOR_E {
        h2 sIA=swp(IA[e]), sRA=swp(RA[e]), sIB=swp(IB[e]), sRB=swp(RB[e]);
        RA[e] = fma2h(K.cc1, RA[e], K.sn1*sIA); IA[e] = fma2h(K.cc1, IA[e], K.nsn1*sRA);
        RB[e] = fma2h(K.cc1, RB[e], K.sn1*sIB); IB[e] = fma2h(K.cc1, IB[e], K.nsn1*sRB); } }
    CRX_LL(2, 1, K.cc1, K.sn1, K.nsn1);     // (3,5)
    {
        if (L2){ FOR_E { cmulh(RA[e],IA[e],K.cl1,K.sl1,K.nsl1); cmulh(RB[e],IB[e],K.cl1,K.sl1,K.nsl1); } }
        h2 T = L2 ? K.ust1 : K.nust1;
        SHF4(4)
        FOR_E {
            RA[e] = fma2h(K.uct1, RA[e], T*oRA[e]); IA[e] = fma2h(K.uct1, IA[e], T*oIA[e]);
            RB[e] = fma2h(K.uct1, RB[e], T*oRB[e]); IB[e] = fma2h(K.uct1, IB[e], T*oIB[e]);
        }
        if (L2){ FOR_E { cmulh(RA[e],IA[e],K.cp1,K.sp1,K.nsp1); cmulh(RB[e],IB[e],K.cp1,K.sp1,K.nsp1); } }
    }
    FOR_E {
        h2 sR=swp(RA[e]), sI=swp(IA[e]);
        h2 nR = fma2h(K.E3,sI, fma2h(K.E2,IA[e], fma2h(K.E1,sR, K.E0*RA[e])));
        h2 nI = fma2h(K.G3,sR, fma2h(K.G2,RA[e], fma2h(K.E1,sI, K.E0*IA[e])));
        RA[e]=nR; IA[e]=nI;
        h2 sR2=swp(RB[e]), sI2=swp(IB[e]);
        h2 nR2 = fma2h(K.E3,sI2, fma2h(K.E2,IB[e], fma2h(K.E1,sR2, K.E0*RB[e])));
        h2 nI2 = fma2h(K.G3,sR2, fma2h(K.G2,RB[e], fma2h(K.E1,sI2, K.E0*IB[e])));
        RB[e]=nR2; IB[e]=nI2;
    }
}

// ---- shared phase-1 macros (R19/R20-verified) ----
#define RY_L(q, M) do { FOR_E { \
    h2 oA = f2h(sx<M>(h2f(A[e]))), oB = f2h(sx<M>(h2f(B[e]))); \
    A[e] = fma2h(cH[e][q], A[e], tsH[e][q]*oA); \
    B[e] = fma2h(cH[e][q], B[e], tsH[e][q]*oB); } \
} while(0)

#define LADDER() do { \
    RINGF(); \
    _Pragma("unroll") for(int cyc=0;cyc<3;++cyc){ \
        RY_L(0,32); RY_L(1,16); RY_L(2,8); RY_L(3,4); RY_L(4,2); RY_L(5,1); \
        FOR_E { h2 nA = fma2h(c6h[e], A[e], ns6h[e]*B[e]); \
                h2 nB = fma2h(s6h[e], A[e], c6h[e]*B[e]); \
                A[e]=nA; B[e]=nB; } \
        FOR_E { A[e] = fma2h(c7h[e], A[e], sv7h[e]*swp(A[e])); \
                B[e] = fma2h(c7h[e], B[e], sv7h[e]*swp(B[e])); } \
        if (cyc < 2) RINGF(); \
    } \
} while(0)

#define BUILD_COEF_INLINE(eeexpr) FOR_E { \
    int ee = (eeexpr); if (ee >= Btot) ee = Btot - 1; \
    const float4* xv = (const float4*)(x + ee*NQ); \
    float4 xa=xv[0], xb=xv[1]; \
    float ang[8]={xa.x,xa.y,xa.z,xa.w,xb.x,xb.y,xb.z,xb.w}; \
    float cq[8], sq[8]; \
    _Pragma("unroll") for(int q=0;q<8;++q) __sincosf(0.5f*ang[q], &sq[q], &cq[q]); \
    _Pragma("unroll") for(int q=0;q<6;++q){ \
        cH[e][q]=mk(cq[q]); \
        tsH[e][q]=u2h(h2u(mk(sq[q])) ^ sm[q]); } \
    c6h[e]=mk(cq[6]); s6h[e]=mk(sq[6]); ns6h[e]=negh(s6h[e]); \
    c7h[e]=mk(cq[7]); sv7h[e]=mk2(-sq[7], sq[7]); \
    float pl = (L5?sq[0]:cq[0])*(L4?sq[1]:cq[1])*(L3?sq[2]:cq[2]) \
             * (L2?sq[3]:cq[3])*(L1?sq[4]:cq[4])*(L0?sq[5]:cq[5]); \
    float pc6=pl*cq[6], ps6=pl*sq[6]; \
    A[e] = mk2(pc6*cq[7], pc6*sq[7]); \
    B[e] = mk2(ps6*cq[7], ps6*sq[7]); \
}

#define REDU(aR, aI, mb, CT) do { \
    _Pragma("unroll") for (int r = 0; r < 4; ++r){ \
        float nv = fmaf(aR[r], aR[r], aI[r]*aI[r]); \
        float o  = sx<1>(nv); \
        float v0 = nv + o, v1 = nv - o; \
        v0 += sx<2>(v0); v1 += sx<2>(v1); \
        v0 += sx<4>(v0); v1 += sx<4>(v1); \
        v0 += sx<8>(v0); v1 += sx<8>(v1); \
        if ((l & 15) == 0){ \
            parts[0][(mb)*16 + g*4 + r][CT] = v0; \
            parts[1][(mb)*16 + g*4 + r][CT] = v1; } \
    } \
} while(0)

// ---- prep_u: 8 blocks x 1024. Each wave builds ONE basis pair. ----
__global__ __launch_bounds__(1024) void qcnn_prep_u(
    const float* __restrict__ crx, const float* __restrict__ u3p,
    unsigned* __restrict__ ws)
{
    __shared__ unsigned cws[48];
    if (threadIdx.x == 0){
        auto PK=[](float lo, float hi)->unsigned{
            unsigned a=__builtin_bit_cast(unsigned short,(_Float16)lo);
            unsigned b=__builtin_bit_cast(unsigned short,(_Float16)hi);
            return a | (b<<16);
        };
        float sc0,cc0,sc1,cc1;
        __sincosf(0.5f*crx[0],&sc0,&cc0);
        __sincosf(0.5f*crx[1],&sc1,&cc1);
        cws[0]=PK(cc0,cc0); cws[1]=PK(sc0,sc0); cws[2]=PK(cc1,cc1); cws[3]=PK(sc1,sc1);
        float th0=u3p[0], ph0=u3p[1], lm0=u3p[2];
        float ust0,uct0; __sincosf(0.5f*th0,&ust0,&uct0);
        cws[4]=PK(uct0,uct0); cws[5]=PK(ust0,ust0); cws[6]=PK(-ust0,-ust0); cws[7]=PK(-ust0,ust0);
        float th1=u3p[3], ph1=u3p[4], lm1=u3p[5];
        float ust1,uct1; __sincosf(0.5f*th1,&ust1,&uct1);
        float sl1,cl1;   __sincosf(lm1,&sl1,&cl1);
        float sp1,cp1;   __sincosf(ph1,&sp1,&cp1);
        cws[8]=PK(uct1,uct1); cws[9]=PK(ust1,ust1); cws[10]=PK(-ust1,-ust1);
        cws[11]=PK(cl1,cl1); cws[12]=PK(sl1,sl1); cws[13]=PK(cp1,cp1); cws[14]=PK(sp1,sp1);
        float cpl1=cp1*cl1-sp1*sl1, spl1=sp1*cl1+cp1*sl1;
        float u01r=-ust1*cl1, u01i=-ust1*sl1;
        float u10r= ust1*cp1, u10i= ust1*sp1;
        float u11r= uct1*cpl1, u11i= uct1*spl1;
        cws[15]=PK(uct1,u11r); cws[16]=PK(u01r,u10r); cws[17]=PK(0.f,-u11i);
        cws[18]=PK(-u01i,-u10i); cws[19]=PK(0.f,u11i); cws[20]=PK(u01i,u10i);
        for(int k=0;k<4;++k){
            float kf=(float)k, sA,cA,sB,cB,sA2,cA2,sB2,cB2;
            __sincosf(lm0*kf,      &sA,&cA);
            __sincosf(lm0*(kf+1.f),&sB,&cB);
            __sincosf(ph0*kf,      &sA2,&cA2);
            __sincosf(ph0*(kf+1.f),&sB2,&cB2);
            unsigned* q = cws + 24 + k*4;
            q[0]=PK(cA,cB); q[1]=PK(sA,sB); q[2]=PK(cA2,cB2); q[3]=PK(sA2,sB2);
        }
    }
    __syncthreads();

    const int l = threadIdx.x & 63;
    const int w = threadIdx.x >> 6;
    const P2C K = load_consts(cws, l);
    const bool pb = __builtin_popcount(l) & 1;
    const int ba0 = (((l&32)|((l^(l>>1))&31)) << 2);
    const int ba1 = ba0 ^ (48<<2);

    const int j0 = blockIdx.x*32 + w*2;
    h2 A[NE], B[NE];
    FOR_E {
        A[e]=(h2){0,0}; B[e]=(h2){0,0};
        const int j = j0 + e;
        if (l == (j >> 2)){
            const int slot = j & 3;
            const _Float16 one = (_Float16)1.f;
            if      (slot==0) A[e].x = one;
            else if (slot==1) A[e].y = one;
            else if (slot==2) B[e].x = one;
            else              B[e].y = one;
        }
    }
    RINGF();
    h2 RA[NE], RB[NE], IA[NE], IB[NE];
    phase2run(l, K, A, B, RA, RB, IA, IB);
    FOR_E {
        const int j = j0 + e;
        *(uint2*)(ws + UR_OFF + j*128 + l*2) = make_uint2(h2u(RA[e]), h2u(RB[e]));
        *(uint2*)(ws + UI_OFF + j*128 + l*2) = make_uint2(h2u(IA[e]), h2u(IB[e]));
    }
}

// ---- prep_frag: repack U16 into B-fragment order. 256 chunks x 64 lanes.
__global__ void qcnn_prep_frag(unsigned* __restrict__ ws){
    const int T = blockIdx.x*256 + threadIdx.x;
    const int chunk = T >> 6, l = T & 63;
    const int ct = chunk >> 4, ri = (chunk >> 3) & 1, ks = chunk & 7;
    const unsigned short* U = (const unsigned short*)(ws + (ri ? UI_OFF : UR_OFF));
    const int n = ct*16 + (l & 15);
    const int g = l >> 4;
    unsigned d[4];
#pragma unroll
    for (int p = 0; p < 4; ++p){
        const int k0 = ks*32 + g*8 + 2*p;
        unsigned lo = U[k0*256 + n];
        unsigned hi = U[(k0+1)*256 + n];
        d[p] = lo | (hi << 16);
    }
    uint4 v; v.x=d[0]; v.y=d[1]; v.z=d[2]; v.w=d[3];
    *(uint4*)(ws + FRAG_OFF + chunk*256 + l*4) = v;
}

// ---- main: 512 threads = 8 waves; M=64 elems/block; 4-pass phase 1;
// GEMM 2 ct x 2 mb-halves per wave, 16 live acc. 3 blocks/CU by LDS. ----
__global__ __launch_bounds__(512) void qcnn_main(
    const float* __restrict__ x,
    const unsigned* __restrict__ wsu,
    const float* __restrict__ w1,
    const float* __restrict__ b1,
    const float* __restrict__ w2,
    const float* __restrict__ b2,
    float* __restrict__ out,
    int Btot)
{
    // Sl: A-tile, fragment order [chunk=mblk*8+ks][granule(64)][16B],
    // granule = (rr | g<<4) ^ ks ^ (g<<1)   (R18-R20 verified)
    __shared__ __align__(16) unsigned char Sl[32*1024];
    __shared__ float parts[2][64][17];       // padded (R18-R20 verified)
    const int tid = threadIdx.x;
    const int l = tid & 63;
    const int w = tid >> 6;                  // wave 0..7
    const int eblk = blockIdx.x * 64;
    const bool L5=(l>>5)&1, L4=(l>>4)&1, L3=(l>>3)&1, L2=(l>>2)&1, L1=(l>>1)&1, L0=l&1;

    const bool pb = __builtin_popcount(l) & 1;
    const int ba0 = (((l&32)|((l^(l>>1))&31)) << 2);
    const int ba1 = ba0 ^ (48<<2);

    const bool bits[6]={L5,L4,L3,L2,L1,L0};
    unsigned sm[6];
#pragma unroll
    for(int q=0;q<6;++q) sm[q] = bits[q] ? 0u : 0x80008000u;

    // ---- phase 1: 4 register-scoped passes, rows w*8 + pass*2 + {0,1}
#pragma unroll 1
    for (int pass = 0; pass < 4; ++pass){
        const int rbase = w*8 + pass*2;
        h2 cH[NE][6], tsH[NE][6];
        h2 c6h[NE], s6h[NE], ns6h[NE], c7h[NE], sv7h[NE];
        h2 A[NE], B[NE];
        BUILD_COEF_INLINE(eblk + rbase + e);
        LADDER();
        FOR_E {
            const int r = rbase + e;
            const int mblk = r >> 4, rr = r & 15;
            const int ks = l >> 3, g2 = (l >> 1) & 3, pp = l & 1;
            const unsigned gran = (unsigned)((rr | (g2<<4)) ^ ks ^ (g2<<1));
            const unsigned off = (unsigned)(((mblk*8 + ks) << 10) | (gran << 4) | (pp << 3));
            *(uint2*)(Sl + off) = make_uint2(h2u(A[e]), h2u(B[e]));
        }
    }
    __syncthreads();

    // ---- GEMM + reduce. Wave w owns col-tiles ct = w*2 + j.
    const int g = l >> 4;
    const unsigned* frag = wsu + FRAG_OFF;
#pragma unroll 1
    for (int j = 0; j < 2; ++j){
        const int ct = w*2 + j;
#pragma unroll 1
        for (int half = 0; half < 2; ++half){
            const int mb0 = half*2, mb1 = half*2 + 1;
            f4 aRa={0,0,0,0}, aIa={0,0,0,0}, aRb={0,0,0,0}, aIb={0,0,0,0};
#pragma unroll
            for (int ks = 0; ks < 8; ++ks){
                h8 br = *(const h8*)(frag + (ct*16 +     ks)*256 + l*4);
                h8 bi = *(const h8*)(frag + (ct*16 + 8 + ks)*256 + l*4);
                const unsigned ga = (unsigned)((l ^ ks ^ (g<<1)) << 4);
                h8 a0 = *(const h8*)(Sl + ((mb0*8 + ks) << 10) + ga);
                h8 a1 = *(const h8*)(Sl + ((mb1*8 + ks) << 10) + ga);
                aRa = __builtin_amdgcn_mfma_f32_16x16x32_f16(a0, br, aRa, 0, 0, 0);
                aIa = __builtin_amdgcn_mfma_f32_16x16x32_f16(a0, bi, aIa, 0, 0, 0);
                aRb = __builtin_amdgcn_mfma_f32_16x16x32_f16(a1, br, aRb, 0, 0, 0);
                aIb = __builtin_amdgcn_mfma_f32_16x16x32_f16(a1, bi, aIb, 0, 0, 0);
            }
            REDU(aRa, aIa, mb0, ct);
            REDU(aRb, aIb, mb1, ct);
        }
    }
    __syncthreads();

    // ---- tail (R20-verified): two halves of 32 elems; lane k reads
    // ct-k's partial; butterfly over 16 lanes; MLP.
#pragma unroll
    for (int half = 0; half < 2; ++half){
        const int elem = (tid >> 4) + half*32;
        const int k = tid & 15;
        float F0 = parts[0][elem][k];
        float F1 = parts[1][elem][k];
        F0 = __int_as_float(__float_as_int(F0) ^ ((k & 1) << 31));  // s3 = (-1)^(ct&1)
        F0 += sx<1>(F0); F0 += sx<2>(F0); F0 += sx<4>(F0); F0 += sx<8>(F0);
        F1 += sx<1>(F1); F1 += sx<2>(F1); F1 += sx<4>(F1); F1 += sx<8>(F1);
        float contrib = 0.0f;
        if (k < 10){
            float z = fmaf(F0, w1[k], fmaf(F1, w1[10+k], b1[k]));
            float ex = __expf(2.0f*z);
            contrib = ((ex-1.0f)/(ex+1.0f)) * w2[k];
        }
        contrib += sx<1>(contrib);
        contrib += sx<2>(contrib);
        contrib += sx<4>(contrib);
        contrib += sx<8>(contrib);
        if (k == 0 && eblk + elem < Btot){
            out[eblk + elem] = 1.0f/(1.0f + __expf(-(contrib + b2[0])));
        }
    }
}

extern "C" void kernel_launch(void* const* d_in, const int* in_sizes, int n_in,
                              void* d_out, int out_size, void* d_ws, size_t ws_size,
                              hipStream_t stream) {
    const float* x   = (const float*)d_in[0];
    const float* crx = (const float*)d_in[1];
    const float* u3p = (const float*)d_in[2];
    const float* w1  = (const float*)d_in[3];
    const float* b1  = (const float*)d_in[4];
    const float* w2  = (const float*)d_in[5];
    const float* b2  = (const float*)d_in[6];
    float* out = (float*)d_out;
    unsigned* ws = (unsigned*)d_ws;

    const int B = in_sizes[0] / NQ;              // 65536
    hipLaunchKernelGGL(qcnn_prep_u,    dim3(8),  dim3(1024), 0, stream, crx, u3p, ws);
    hipLaunchKernelGGL(qcnn_prep_frag, dim3(64), dim3(256),  0, stream, ws);
    hipLaunchKernelGGL(qcnn_main, dim3((B + 63) / 64), dim3(512), 0, stream,
                       x, ws, w1, b1, w2, b2, out, B);
}